// Round 1
// baseline (74.791 us; speedup 1.0000x reference)
//
#include <hip/hip_runtime.h>
#include <math.h>

// TrajParamIndex layout
// X=0, Y=1, Z=2, VX=3, VY=4, VZ=5, AX=6, AY=7, AZ=8, YAW=9, LENGTH=10, WIDTH=11, HEIGHT=12, STATIC=13
#define N_PRED 900
#define N_GT   128
#define PB     16    // preds per block

__device__ __forceinline__ void compute_aabb(const float* __restrict__ t,
                                             float t0, float t1,
                                             float& minx, float& miny,
                                             float& maxx, float& maxy) {
    float x_e = t[0], y_e = t[1];
    float vx  = t[3], vy  = t[4];
    float ax  = t[6], ay  = t[7];
    float x_s = x_e + vx * t0 + 0.5f * ax * t0 * t0;
    float y_s = y_e + vy * t0 + 0.5f * ay * t0 * t0;
    float l   = t[10], w = t[11];
    float yaw0 = t[9];
    float x_m = (x_s + x_e) * 0.5f;
    float y_m = (y_s + y_e) * 0.5f;
    float t_mid = (t0 + t1) * 0.5f;
    float vxm = vx + ax * t_mid, vym = vy + ay * t_mid;
    float dx = x_e - x_s, dy = y_e - y_s;
    float move = sqrtf(dx * dx + dy * dy);
    float l_ext = l + move;
    float speed = sqrtf(vxm * vxm + vym * vym);
    bool  stat  = t[13] > 0.5f;
    float yaw = ((speed > 0.2f) && !stat) ? atan2f(vym, vxm) : yaw0;
    float c, s;
    sincosf(yaw, &s, &c);
    float hl = l_ext * 0.5f, hw = w * 0.5f;
    // corners are all 4 sign combos of (+-hl*c +- hw*s, +-hl*s +- hw*c)
    float ex = fabsf(hl * c) + fabsf(hw * s);
    float ey = fabsf(hl * s) + fabsf(hw * c);
    minx = x_m - ex; maxx = x_m + ex;
    miny = y_m - ey; maxy = y_m + ey;
}

__global__ __launch_bounds__(256) void traj_iou_kernel(
        const float* __restrict__ pred,   // [B, N_PRED, 14]
        const float* __restrict__ gt,     // [B, N_GT, 14]
        const float* __restrict__ frames, // [nframes]
        float* __restrict__ out,          // [B, N_PRED, N_GT]
        int nframes) {
    __shared__ float g_minx[N_GT], g_miny[N_GT], g_maxx[N_GT], g_maxy[N_GT], g_area[N_GT];
    __shared__ float p_minx[PB], p_miny[PB], p_maxx[PB], p_maxy[PB], p_area[PB];

    const int b   = blockIdx.y;
    const int p0  = blockIdx.x * PB;
    const int tid = threadIdx.x;

    const float t0 = frames[0];
    const float t1 = frames[nframes - 1];

    if (tid < N_GT) {
        float mnx, mny, mxx, mxy;
        compute_aabb(gt + ((size_t)b * N_GT + tid) * 14, t0, t1, mnx, mny, mxx, mxy);
        g_minx[tid] = mnx; g_miny[tid] = mny;
        g_maxx[tid] = mxx; g_maxy[tid] = mxy;
        g_area[tid] = (mxx - mnx) * (mxy - mny);
    } else if (tid - N_GT < PB) {
        const int pl = tid - N_GT;
        const int p  = p0 + pl;
        if (p < N_PRED) {
            float mnx, mny, mxx, mxy;
            compute_aabb(pred + ((size_t)b * N_PRED + p) * 14, t0, t1, mnx, mny, mxx, mxy);
            p_minx[pl] = mnx; p_miny[pl] = mny;
            p_maxx[pl] = mxx; p_maxy[pl] = mxy;
            p_area[pl] = (mxx - mnx) * (mxy - mny);
        }
    }
    __syncthreads();

    const int g = tid & (N_GT - 1);
    for (int pl = tid >> 7; pl < PB; pl += 2) {
        const int p = p0 + pl;
        if (p >= N_PRED) break;
        const float ix1 = fmaxf(p_minx[pl], g_minx[g]);
        const float iy1 = fmaxf(p_miny[pl], g_miny[g]);
        const float ix2 = fminf(p_maxx[pl], g_maxx[g]);
        const float iy2 = fminf(p_maxy[pl], g_maxy[g]);
        const float inter = fmaxf(ix2 - ix1, 0.0f) * fmaxf(iy2 - iy1, 0.0f);
        const float uni   = fmaxf(p_area[pl] + g_area[g] - inter, 1e-8f);
        out[((size_t)b * N_PRED + p) * N_GT + g] = inter / uni;
    }
}

extern "C" void kernel_launch(void* const* d_in, const int* in_sizes, int n_in,
                              void* d_out, int out_size, void* d_ws, size_t ws_size,
                              hipStream_t stream) {
    const float* pred   = (const float*)d_in[0];
    const float* gt     = (const float*)d_in[1];
    const float* frames = (const float*)d_in[2];
    float* out = (float*)d_out;

    const int nframes = in_sizes[2];
    const int B = in_sizes[0] / (N_PRED * 14);

    dim3 grid((N_PRED + PB - 1) / PB, B);
    traj_iou_kernel<<<grid, 256, 0, stream>>>(pred, gt, frames, out, nframes);
}

// Round 7
// 74.295 us; speedup vs baseline: 1.0067x; 1.0067x over previous
//
#include <hip/hip_runtime.h>
#include <math.h>

// TrajParamIndex layout
// X=0, Y=1, Z=2, VX=3, VY=4, VZ=5, AX=6, AY=7, AZ=8, YAW=9, LENGTH=10, WIDTH=11, HEIGHT=12, STATIC=13
#define N_PRED 900
#define N_GT   128
#define ROWS   32    // pred rows per block in pair kernel

__device__ __forceinline__ void compute_aabb(const float* __restrict__ t,
                                             float t0, float t1,
                                             float& minx, float& miny,
                                             float& maxx, float& maxy) {
    float x_e = t[0], y_e = t[1];
    float vx  = t[3], vy  = t[4];
    float ax  = t[6], ay  = t[7];
    float x_s = x_e + vx * t0 + 0.5f * ax * t0 * t0;
    float y_s = y_e + vy * t0 + 0.5f * ay * t0 * t0;
    float l   = t[10], w = t[11];
    float yaw0 = t[9];
    float x_m = (x_s + x_e) * 0.5f;
    float y_m = (y_s + y_e) * 0.5f;
    float t_mid = (t0 + t1) * 0.5f;
    float vxm = vx + ax * t_mid, vym = vy + ay * t_mid;
    float dx = x_e - x_s, dy = y_e - y_s;
    float move = sqrtf(dx * dx + dy * dy);
    float l_ext = l + move;
    float speed = sqrtf(vxm * vxm + vym * vym);
    bool  stat  = t[13] > 0.5f;
    float yaw = ((speed > 0.2f) && !stat) ? atan2f(vym, vxm) : yaw0;
    float c, s;
    sincosf(yaw, &s, &c);
    float hl = l_ext * 0.5f, hw = w * 0.5f;
    // corners are all 4 sign combos of (+-hl*c +- hw*s, +-hl*s +- hw*c)
    float ex = fabsf(hl * c) + fabsf(hw * s);
    float ey = fabsf(hl * s) + fabsf(hw * c);
    minx = x_m - ex; maxx = x_m + ex;
    miny = y_m - ey; maxy = y_m + ey;
}

// ws SoA layout (floats):
//   pred: minx[NP] miny[NP] maxx[NP] maxy[NP] area[NP]   NP = B*900
//   gt:   minx[NG] miny[NG] maxx[NG] maxy[NG] area[NG]   NG = B*128
__global__ __launch_bounds__(256) void aabb_kernel(
        const float* __restrict__ pred, const float* __restrict__ gt,
        const float* __restrict__ frames, float* __restrict__ ws,
        int nframes, int B) {
    const size_t NP = (size_t)B * N_PRED;
    const size_t NG = (size_t)B * N_GT;
    const size_t idx = (size_t)blockIdx.x * blockDim.x + threadIdx.x;
    const float t0 = frames[0];
    const float t1 = frames[nframes - 1];

    if (idx < NP) {
        float mnx, mny, mxx, mxy;
        compute_aabb(pred + idx * 14, t0, t1, mnx, mny, mxx, mxy);
        ws[idx]          = mnx;
        ws[NP + idx]     = mny;
        ws[2 * NP + idx] = mxx;
        ws[3 * NP + idx] = mxy;
        ws[4 * NP + idx] = (mxx - mnx) * (mxy - mny);
    } else if (idx < NP + NG) {
        const size_t j = idx - NP;
        float mnx, mny, mxx, mxy;
        compute_aabb(gt + j * 14, t0, t1, mnx, mny, mxx, mxy);
        float* gws = ws + 5 * NP;
        gws[j]          = mnx;
        gws[NG + j]     = mny;
        gws[2 * NG + j] = mxx;
        gws[3 * NG + j] = mxy;
        gws[4 * NG + j] = (mxx - mnx) * (mxy - mny);
    }
}

__global__ __launch_bounds__(256) void pair_kernel(
        const float* __restrict__ ws, float* __restrict__ out, int B) {
    const size_t NP = (size_t)B * N_PRED;
    const size_t NG = (size_t)B * N_GT;
    const float* __restrict__ pminx = ws;
    const float* __restrict__ pminy = ws + NP;
    const float* __restrict__ pmaxx = ws + 2 * NP;
    const float* __restrict__ pmaxy = ws + 3 * NP;
    const float* __restrict__ parea = ws + 4 * NP;
    const float* __restrict__ gws   = ws + 5 * NP;

    __shared__ float s_gminx[N_GT], s_gminy[N_GT], s_gmaxx[N_GT], s_gmaxy[N_GT], s_garea[N_GT];
    __shared__ float s_p[5][ROWS];

    const int b   = blockIdx.y;
    const int p0  = blockIdx.x * ROWS;
    const int tid = threadIdx.x;

    if (tid < N_GT) {
        const size_t j = (size_t)b * N_GT + tid;
        s_gminx[tid] = gws[j];
        s_gminy[tid] = gws[NG + j];
        s_gmaxx[tid] = gws[2 * NG + j];
        s_gmaxy[tid] = gws[3 * NG + j];
        s_garea[tid] = gws[4 * NG + j];
    } else if (tid - N_GT < ROWS) {
        const int pl = tid - N_GT;
        const int p  = p0 + pl;
        if (p < N_PRED) {
            const size_t j = (size_t)b * N_PRED + p;
            s_p[0][pl] = pminx[j];
            s_p[1][pl] = pminy[j];
            s_p[2][pl] = pmaxx[j];
            s_p[3][pl] = pmaxy[j];
            s_p[4][pl] = parea[j];
        }
    }
    __syncthreads();

    const int g4 = tid & 31;          // float4 index along gt axis
    const int r0 = tid >> 5;          // 8 row-slots per 256 threads

    // hoist the gt fragment (same for all rows this thread touches)
    const float4 gx1 = *(const float4*)&s_gminx[g4 * 4];
    const float4 gy1 = *(const float4*)&s_gminy[g4 * 4];
    const float4 gx2 = *(const float4*)&s_gmaxx[g4 * 4];
    const float4 gy2 = *(const float4*)&s_gmaxy[g4 * 4];
    const float4 gar = *(const float4*)&s_garea[g4 * 4];

    for (int r = r0; r < ROWS; r += 8) {
        const int p = p0 + r;
        if (p >= N_PRED) break;
        const float px1 = s_p[0][r], py1 = s_p[1][r];
        const float px2 = s_p[2][r], py2 = s_p[3][r];
        const float par = s_p[4][r];
        float4 res;
        {
            float ix1 = fmaxf(px1, gx1.x), iy1 = fmaxf(py1, gy1.x);
            float ix2 = fminf(px2, gx2.x), iy2 = fminf(py2, gy2.x);
            float inter = fmaxf(ix2 - ix1, 0.f) * fmaxf(iy2 - iy1, 0.f);
            res.x = inter / fmaxf(par + gar.x - inter, 1e-8f);
        }
        {
            float ix1 = fmaxf(px1, gx1.y), iy1 = fmaxf(py1, gy1.y);
            float ix2 = fminf(px2, gx2.y), iy2 = fminf(py2, gy2.y);
            float inter = fmaxf(ix2 - ix1, 0.f) * fmaxf(iy2 - iy1, 0.f);
            res.y = inter / fmaxf(par + gar.y - inter, 1e-8f);
        }
        {
            float ix1 = fmaxf(px1, gx1.z), iy1 = fmaxf(py1, gy1.z);
            float ix2 = fminf(px2, gx2.z), iy2 = fminf(py2, gy2.z);
            float inter = fmaxf(ix2 - ix1, 0.f) * fmaxf(iy2 - iy1, 0.f);
            res.z = inter / fmaxf(par + gar.z - inter, 1e-8f);
        }
        {
            float ix1 = fmaxf(px1, gx1.w), iy1 = fmaxf(py1, gy1.w);
            float ix2 = fminf(px2, gx2.w), iy2 = fminf(py2, gy2.w);
            float inter = fmaxf(ix2 - ix1, 0.f) * fmaxf(iy2 - iy1, 0.f);
            res.w = inter / fmaxf(par + gar.w - inter, 1e-8f);
        }
        *(float4*)&out[((size_t)b * N_PRED + p) * N_GT + g4 * 4] = res;
    }
}

extern "C" void kernel_launch(void* const* d_in, const int* in_sizes, int n_in,
                              void* d_out, int out_size, void* d_ws, size_t ws_size,
                              hipStream_t stream) {
    const float* pred   = (const float*)d_in[0];
    const float* gt     = (const float*)d_in[1];
    const float* frames = (const float*)d_in[2];
    float* out = (float*)d_out;
    float* ws  = (float*)d_ws;

    const int nframes = in_sizes[2];
    const int B = in_sizes[0] / (N_PRED * 14);

    const size_t total = (size_t)B * (N_PRED + N_GT);
    const int blocks1 = (int)((total + 255) / 256);
    aabb_kernel<<<blocks1, 256, 0, stream>>>(pred, gt, frames, ws, nframes, B);

    dim3 grid2((N_PRED + ROWS - 1) / ROWS, B);
    pair_kernel<<<grid2, 256, 0, stream>>>(ws, out, B);
}

// Round 12
// 73.142 us; speedup vs baseline: 1.0225x; 1.0158x over previous
//
#include <hip/hip_runtime.h>
#include <math.h>

// TrajParamIndex layout
// X=0, Y=1, Z=2, VX=3, VY=4, VZ=5, AX=6, AY=7, AZ=8, YAW=9, LENGTH=10, WIDTH=11, HEIGHT=12, STATIC=13
#define N_PRED 900
#define N_GT   128
#define ROWS   32    // preds per block

__device__ __forceinline__ void compute_aabb(const float* __restrict__ t,
                                             float t0, float t1,
                                             float& minx, float& miny,
                                             float& maxx, float& maxy) {
    float x_e = t[0], y_e = t[1];
    float vx  = t[3], vy  = t[4];
    float ax  = t[6], ay  = t[7];
    float x_s = x_e + vx * t0 + 0.5f * ax * t0 * t0;
    float y_s = y_e + vy * t0 + 0.5f * ay * t0 * t0;
    float l   = t[10], w = t[11];
    float yaw0 = t[9];
    float x_m = (x_s + x_e) * 0.5f;
    float y_m = (y_s + y_e) * 0.5f;
    float t_mid = (t0 + t1) * 0.5f;
    float vxm = vx + ax * t_mid, vym = vy + ay * t_mid;
    float dx = x_e - x_s, dy = y_e - y_s;
    float move = sqrtf(dx * dx + dy * dy);
    float l_ext = l + move;
    float speed = sqrtf(vxm * vxm + vym * vym);
    bool  stat  = t[13] > 0.5f;
    float yaw = ((speed > 0.2f) && !stat) ? atan2f(vym, vxm) : yaw0;
    float c, s;
    sincosf(yaw, &s, &c);
    float hl = l_ext * 0.5f, hw = w * 0.5f;
    // corners are all 4 sign combos of (+-hl*c +- hw*s, +-hl*s +- hw*c)
    float ex = fabsf(hl * c) + fabsf(hw * s);
    float ey = fabsf(hl * s) + fabsf(hw * c);
    minx = x_m - ex; maxx = x_m + ex;
    miny = y_m - ey; maxy = y_m + ey;
}

__global__ __launch_bounds__(256) void fused_iou_kernel(
        const float* __restrict__ pred,   // [B, N_PRED, 14]
        const float* __restrict__ gt,     // [B, N_GT, 14]
        const float* __restrict__ frames, // [nframes]
        float* __restrict__ out,          // [B, N_PRED, N_GT]
        int nframes) {
    __shared__ float s_g[5][N_GT];   // minx,miny,maxx,maxy,area
    __shared__ float s_p[5][ROWS];

    const int b   = blockIdx.y;
    const int p0  = blockIdx.x * ROWS;
    const int tid = threadIdx.x;

    const float t0 = frames[0];
    const float t1 = frames[nframes - 1];

    if (tid < N_GT) {
        float mnx, mny, mxx, mxy;
        compute_aabb(gt + ((size_t)b * N_GT + tid) * 14, t0, t1, mnx, mny, mxx, mxy);
        s_g[0][tid] = mnx; s_g[1][tid] = mny;
        s_g[2][tid] = mxx; s_g[3][tid] = mxy;
        s_g[4][tid] = (mxx - mnx) * (mxy - mny);
    } else if (tid - N_GT < ROWS) {
        const int pl = tid - N_GT;
        const int p  = p0 + pl;
        if (p < N_PRED) {
            float mnx, mny, mxx, mxy;
            compute_aabb(pred + ((size_t)b * N_PRED + p) * 14, t0, t1, mnx, mny, mxx, mxy);
            s_p[0][pl] = mnx; s_p[1][pl] = mny;
            s_p[2][pl] = mxx; s_p[3][pl] = mxy;
            s_p[4][pl] = (mxx - mnx) * (mxy - mny);
        }
    }
    __syncthreads();

    const int g4 = tid & 31;          // float4 index along gt axis (32*4 = 128)
    const int r0 = tid >> 5;          // 8 row-slots per 256 threads

    // hoist the gt fragment (same for all rows this thread touches)
    const float4 gx1 = *(const float4*)&s_g[0][g4 * 4];
    const float4 gy1 = *(const float4*)&s_g[1][g4 * 4];
    const float4 gx2 = *(const float4*)&s_g[2][g4 * 4];
    const float4 gy2 = *(const float4*)&s_g[3][g4 * 4];
    const float4 gar = *(const float4*)&s_g[4][g4 * 4];

    for (int r = r0; r < ROWS; r += 8) {
        const int p = p0 + r;
        if (p >= N_PRED) break;
        const float px1 = s_p[0][r], py1 = s_p[1][r];
        const float px2 = s_p[2][r], py2 = s_p[3][r];
        const float par = s_p[4][r];
        float4 res;
        {
            float ix1 = fmaxf(px1, gx1.x), iy1 = fmaxf(py1, gy1.x);
            float ix2 = fminf(px2, gx2.x), iy2 = fminf(py2, gy2.x);
            float inter = fmaxf(ix2 - ix1, 0.f) * fmaxf(iy2 - iy1, 0.f);
            res.x = inter / fmaxf(par + gar.x - inter, 1e-8f);
        }
        {
            float ix1 = fmaxf(px1, gx1.y), iy1 = fmaxf(py1, gy1.y);
            float ix2 = fminf(px2, gx2.y), iy2 = fminf(py2, gy2.y);
            float inter = fmaxf(ix2 - ix1, 0.f) * fmaxf(iy2 - iy1, 0.f);
            res.y = inter / fmaxf(par + gar.y - inter, 1e-8f);
        }
        {
            float ix1 = fmaxf(px1, gx1.z), iy1 = fmaxf(py1, gy1.z);
            float ix2 = fminf(px2, gx2.z), iy2 = fminf(py2, gy2.z);
            float inter = fmaxf(ix2 - ix1, 0.f) * fmaxf(iy2 - iy1, 0.f);
            res.z = inter / fmaxf(par + gar.z - inter, 1e-8f);
        }
        {
            float ix1 = fmaxf(px1, gx1.w), iy1 = fmaxf(py1, gy1.w);
            float ix2 = fminf(px2, gx2.w), iy2 = fminf(py2, gy2.w);
            float inter = fmaxf(ix2 - ix1, 0.f) * fmaxf(iy2 - iy1, 0.f);
            res.w = inter / fmaxf(par + gar.w - inter, 1e-8f);
        }
        *(float4*)&out[((size_t)b * N_PRED + p) * N_GT + g4 * 4] = res;
    }
}

extern "C" void kernel_launch(void* const* d_in, const int* in_sizes, int n_in,
                              void* d_out, int out_size, void* d_ws, size_t ws_size,
                              hipStream_t stream) {
    const float* pred   = (const float*)d_in[0];
    const float* gt     = (const float*)d_in[1];
    const float* frames = (const float*)d_in[2];
    float* out = (float*)d_out;

    const int nframes = in_sizes[2];
    const int B = in_sizes[0] / (N_PRED * 14);

    dim3 grid((N_PRED + ROWS - 1) / ROWS, B);
    fused_iou_kernel<<<grid, 256, 0, stream>>>(pred, gt, frames, out, nframes);
}